// Round 1
// baseline (524.529 us; speedup 1.0000x reference)
//
#include <hip/hip_runtime.h>
#include <hip/hip_bf16.h>
#include <stdint.h>

#define NROW 8192
#define NCOL 8192
#define INF 256
#define OUTF 256

typedef __attribute__((ext_vector_type(4))) float f32x4;
typedef __attribute__((ext_vector_type(8))) short s16x8;
typedef __attribute__((ext_vector_type(4))) int i32x4;
typedef __attribute__((ext_vector_type(2))) unsigned int u32x2;

__device__ __forceinline__ short f2bf(float f) {
  unsigned int u = __builtin_bit_cast(unsigned int, f);
  unsigned int r = (u + 0x7FFFu + ((u >> 16) & 1u)) >> 16;   // RTNE
  return (short)r;
}
__device__ __forceinline__ float bf2f(short s) {
  unsigned int u = ((unsigned int)(unsigned short)s) << 16;
  return __builtin_bit_cast(float, u);
}

// global fp32 16B-chunk -> LDS, async DMA (wave-uniform LDS base + lane*16)
#define GLDS(g, l)                                                            \
  __builtin_amdgcn_global_load_lds(                                           \
      (const __attribute__((address_space(1))) void*)(g),                     \
      (__attribute__((address_space(3))) void*)(l), 16, 0, 0)

// ---------------------------------------------------------------------------
// K1: deg[i] = 1 + sum_j A[i,j];  dis[i] = 1/sqrt(deg)
// one wave per row, 4 rows/block
// ---------------------------------------------------------------------------
__global__ __launch_bounds__(256) void k_deg(const float* __restrict__ A,
                                             float* __restrict__ dis) {
  const int wave = threadIdx.x >> 6, lane = threadIdx.x & 63;
  const int row = (blockIdx.x << 2) + wave;
  const f32x4* Ar = (const f32x4*)(A + (size_t)row * NCOL);
  float s = 0.f;
#pragma unroll 8
  for (int it = 0; it < 32; ++it) {
    f32x4 v = Ar[(it << 6) + lane];
    s += (v.x + v.y) + (v.z + v.w);
  }
#pragma unroll
  for (int off = 32; off > 0; off >>= 1) s += __shfl_down(s, off, 64);
  if (lane == 0) dis[row] = 1.0f / sqrtf(s + 1.0f);
}

// ---------------------------------------------------------------------------
// K2: Yt[f][j] = bf16(X[j][f]*dis[j])  (transposed, B-operand layout)
//     Yrm[j][f] = bf16(X[j][f]*dis[j]) (row-major, for +I term)
//     Wb = bf16(W)
// blocks 0..127: 64-row X tiles; blocks 128..159: W convert
// ---------------------------------------------------------------------------
__global__ __launch_bounds__(256) void k_prep(const float* __restrict__ X,
                                              const float* __restrict__ W,
                                              const float* __restrict__ dis,
                                              short* __restrict__ Yt,
                                              short* __restrict__ Yrm,
                                              short* __restrict__ Wb) {
  __shared__ short T[256][72];   // [f][j], stride 72 (144B, 16B-aligned rows)
  __shared__ float sd[64];
  const int tid = threadIdx.x;

  if (blockIdx.x >= 128) {       // W convert: 32 blocks * 256 thr * 8 elems
    const int idx8 = (((int)blockIdx.x - 128) * 256 + tid) << 3;
    f32x4 a = *(const f32x4*)(W + idx8);
    f32x4 b = *(const f32x4*)(W + idx8 + 4);
    s16x8 o;
    o[0] = f2bf(a.x); o[1] = f2bf(a.y); o[2] = f2bf(a.z); o[3] = f2bf(a.w);
    o[4] = f2bf(b.x); o[5] = f2bf(b.y); o[6] = f2bf(b.z); o[7] = f2bf(b.w);
    *(s16x8*)(Wb + idx8) = o;
    return;
  }

  const int jb = blockIdx.x << 6;
  if (tid < 64) sd[tid] = dis[jb + tid];
  __syncthreads();
#pragma unroll
  for (int i = 0; i < 16; ++i) {
    const int flat = (i << 8) + tid;     // float4 id in 64x256 tile
    const int j = flat >> 6;
    const int fc = flat & 63;            // f = fc*4
    f32x4 v = *(const f32x4*)(X + (size_t)(jb + j) * INF + (fc << 2));
    const float d = sd[j];
    short b0 = f2bf(v.x * d), b1 = f2bf(v.y * d);
    short b2 = f2bf(v.z * d), b3 = f2bf(v.w * d);
    T[(fc << 2) + 0][j] = b0;
    T[(fc << 2) + 1][j] = b1;
    T[(fc << 2) + 2][j] = b2;
    T[(fc << 2) + 3][j] = b3;
    u32x2 p;
    p.x = (unsigned int)(unsigned short)b0 | ((unsigned int)(unsigned short)b1 << 16);
    p.y = (unsigned int)(unsigned short)b2 | ((unsigned int)(unsigned short)b3 << 16);
    *(u32x2*)(Yrm + (size_t)(jb + j) * INF + (fc << 2)) = p;
  }
  __syncthreads();
#pragma unroll
  for (int c = 0; c < 8; ++c) {          // f = tid, write 8 j at a time
    s16x8 v = *(const s16x8*)&T[tid][c << 3];
    *(s16x8*)(Yt + (size_t)tid * NROW + jb + (c << 3)) = v;
  }
}

// ---------------------------------------------------------------------------
// K3: P[sp] += A[rows, ksp] @ Yt^T[ksp, :256]   (bf16 MFMA, fp32 acc)
// BM=64 BN=256 BK=32, 4 waves x (64x64), split-K, A via global_load_lds
// into 3-rotating LDS buffers (1 barrier/step, issue-after-barrier),
// B-frags direct from L2-hot Yt with distance-1 register prefetch.
// ---------------------------------------------------------------------------
__global__ __launch_bounds__(256, 2) void k_gemm(const float* __restrict__ A,
                                                 const short* __restrict__ Yt,
                                                 float* __restrict__ P,
                                                 int splits) {
  __shared__ float Ab[3][2048];          // 3 x (64 rows x 32 fp32), swizzled
  const int tid = threadIdx.x;
  const int w = tid >> 6, l = tid & 63, lr = l & 15, lq = l >> 4;
  const int rb = blockIdx.x, sp = blockIdx.y;
  const int row0 = rb << 6;
  const int kspan = NCOL / splits;
  const int k0 = sp * kspan;
  const int steps = kspan >> 5;
  const int wbase = tid & ~63;           // w*64 (wave-uniform)

  // DMA global addresses: chunk p in [0,512): n=p>>3, cpos=p&7, c=cpos^(n&7)
  const int n0 = tid >> 3,         c0 = (tid & 7) ^ (n0 & 7);
  const int n1 = (tid + 256) >> 3, c1 = ((tid + 256) & 7) ^ (n1 & 7);
  const char* gA0 =
      (const char*)(A + (size_t)(row0 + n0) * NCOL + k0) + (c0 << 4);
  const char* gA1 =
      (const char*)(A + (size_t)(row0 + n1) * NCOL + k0) + (c1 << 4);

  const short* Bbase = Yt + (size_t)((w << 6) + lr) * NROW + k0 + (lq << 3);

  f32x4 acc[4][4];
#pragma unroll
  for (int rt = 0; rt < 4; ++rt)
#pragma unroll
    for (int ct = 0; ct < 4; ++ct) acc[rt][ct] = (f32x4){0.f, 0.f, 0.f, 0.f};

  // prologue: DMA(0) + B(0)
  GLDS(gA0, &Ab[0][wbase << 2]);
  GLDS(gA1, &Ab[0][(256 + wbase) << 2]);
  i32x4 bB[4];
#pragma unroll
  for (int ct = 0; ct < 4; ++ct)
    bB[ct] = *(const i32x4*)(Bbase + (size_t)(ct << 4) * NROW);

  for (int s = 0; s < steps; ++s) {
    __syncthreads();  // vmcnt(0): DMA(s)+B(s) arrived; buffer-reuse fence

    if (s + 1 < steps) {                 // DMA(s+1) into buffer (s+1)%3
      const int nb = (s + 1) % 3;
      GLDS(gA0 + ((size_t)(s + 1) << 7), &Ab[nb][wbase << 2]);
      GLDS(gA1 + ((size_t)(s + 1) << 7), &Ab[nb][(256 + wbase) << 2]);
    }

    s16x8 bfr[4];
#pragma unroll
    for (int ct = 0; ct < 4; ++ct) bfr[ct] = __builtin_bit_cast(s16x8, bB[ct]);
    if (s + 1 < steps) {                 // prefetch B(s+1)
#pragma unroll
      for (int ct = 0; ct < 4; ++ct)
        bB[ct] = *(const i32x4*)(Bbase + (size_t)(ct << 4) * NROW +
                                 ((size_t)(s + 1) << 5));
    }

    // A-frags from Ab[s%3] (swizzled), cvt fp32->bf16
    const float* buf = Ab[s % 3];
    s16x8 af[4];
#pragma unroll
    for (int rt = 0; rt < 4; ++rt) {
      const int n = (rt << 4) + lr;
      const int cp0 = ((lq << 1) + 0) ^ (n & 7);
      const int cp1 = ((lq << 1) + 1) ^ (n & 7);
      f32x4 u0 = *(const f32x4*)(buf + (n << 5) + (cp0 << 2));
      f32x4 u1 = *(const f32x4*)(buf + (n << 5) + (cp1 << 2));
      s16x8 t;
      t[0] = f2bf(u0.x); t[1] = f2bf(u0.y); t[2] = f2bf(u0.z); t[3] = f2bf(u0.w);
      t[4] = f2bf(u1.x); t[5] = f2bf(u1.y); t[6] = f2bf(u1.z); t[7] = f2bf(u1.w);
      af[rt] = t;
    }
#pragma unroll
    for (int rt = 0; rt < 4; ++rt)
#pragma unroll
      for (int ct = 0; ct < 4; ++ct)
        acc[rt][ct] = __builtin_amdgcn_mfma_f32_16x16x32_bf16(
            af[rt], bfr[ct], acc[rt][ct], 0, 0, 0);
  }

  // epilogue: raw partial (normalization applied in K4)
  float* Pp = P + ((size_t)sp << 21);
#pragma unroll
  for (int rt = 0; rt < 4; ++rt)
#pragma unroll
    for (int ct = 0; ct < 4; ++ct) {
      const int col = (w << 6) + (ct << 4) + lr;
      const int row = row0 + (rt << 4) + (lq << 2);
#pragma unroll
      for (int r = 0; r < 4; ++r)
        Pp[((size_t)(row + r) << 8) + col] = acc[rt][ct][r];
    }
}

// ---------------------------------------------------------------------------
// K4: h = dis[i]*(sum_sp P + Yrm[i])  (bf16) ; out = h @ Wb^T + b  (fp32)
// 64 rows x 128 cols per block, 2 waves x (64x64)
// ---------------------------------------------------------------------------
__global__ __launch_bounds__(128) void k_out(const float* __restrict__ P,
                                             const short* __restrict__ Yrm,
                                             const short* __restrict__ Wb,
                                             const float* __restrict__ dis,
                                             const float* __restrict__ bias,
                                             float* __restrict__ out,
                                             int splits) {
  const int w = threadIdx.x >> 6, l = threadIdx.x & 63, lr = l & 15, lq = l >> 4;
  const int row0 = (int)blockIdx.x << 6;
  const int col0 = ((int)blockIdx.y << 7) + (w << 6);

  f32x4 acc[4][4];
#pragma unroll
  for (int rt = 0; rt < 4; ++rt)
#pragma unroll
    for (int ct = 0; ct < 4; ++ct) acc[rt][ct] = (f32x4){0.f, 0.f, 0.f, 0.f};

  for (int s = 0; s < 8; ++s) {
    const int f0 = (s << 5) + (lq << 3);
    s16x8 wf[4];
#pragma unroll
    for (int ct = 0; ct < 4; ++ct)
      wf[ct] = *(const s16x8*)(Wb + ((size_t)(col0 + (ct << 4) + lr) << 8) + f0);
#pragma unroll
    for (int rt = 0; rt < 4; ++rt) {
      const int row = row0 + (rt << 4) + lr;
      const float* p = P + ((size_t)row << 8) + f0;
      f32x4 u0 = *(const f32x4*)(p);
      f32x4 u1 = *(const f32x4*)(p + 4);
      for (int sp = 1; sp < splits; ++sp) {
        const float* q = p + ((size_t)sp << 21);
        u0 += *(const f32x4*)(q);
        u1 += *(const f32x4*)(q + 4);
      }
      s16x8 y = *(const s16x8*)(Yrm + ((size_t)row << 8) + f0);
      const float di = dis[row];
      s16x8 af;
      af[0] = f2bf((u0.x + bf2f(y[0])) * di);
      af[1] = f2bf((u0.y + bf2f(y[1])) * di);
      af[2] = f2bf((u0.z + bf2f(y[2])) * di);
      af[3] = f2bf((u0.w + bf2f(y[3])) * di);
      af[4] = f2bf((u1.x + bf2f(y[4])) * di);
      af[5] = f2bf((u1.y + bf2f(y[5])) * di);
      af[6] = f2bf((u1.z + bf2f(y[6])) * di);
      af[7] = f2bf((u1.w + bf2f(y[7])) * di);
#pragma unroll
      for (int ct = 0; ct < 4; ++ct)
        acc[rt][ct] = __builtin_amdgcn_mfma_f32_16x16x32_bf16(
            af, wf[ct], acc[rt][ct], 0, 0, 0);
    }
  }

#pragma unroll
  for (int ct = 0; ct < 4; ++ct) {
    const int col = col0 + (ct << 4) + lr;
    const float bb = bias[col];
#pragma unroll
    for (int rt = 0; rt < 4; ++rt) {
      const int row = row0 + (rt << 4) + (lq << 2);
#pragma unroll
      for (int r = 0; r < 4; ++r)
        out[((size_t)(row + r) << 8) + col] = acc[rt][ct][r] + bb;
    }
  }
}

// ---------------------------------------------------------------------------
extern "C" void kernel_launch(void* const* d_in, const int* in_sizes, int n_in,
                              void* d_out, int out_size, void* d_ws,
                              size_t ws_size, hipStream_t stream) {
  const float* X = (const float*)d_in[0];
  const float* A = (const float*)d_in[1];
  const float* W = (const float*)d_in[2];
  const float* b = (const float*)d_in[3];
  float* out = (float*)d_out;

  char* ws = (char*)d_ws;
  float* dis = (float*)ws;                                   // 32 KB
  short* Yt  = (short*)(ws + 32768);                         // 4 MB
  short* Yrm = (short*)(ws + 32768 + 4194304);               // 4 MB
  short* Wb  = (short*)(ws + 32768 + 2 * 4194304);           // 128 KB
  const size_t base = 32768 + 2ull * 4194304 + 131072;
  float* P   = (float*)(ws + base);                          // splits * 8 MB

  const int splits = (ws_size >= base + 4ull * 8388608) ? 4 : 1;

  k_deg<<<2048, 256, 0, stream>>>(A, dis);
  k_prep<<<160, 256, 0, stream>>>(X, W, dis, Yt, Yrm, Wb);
  k_gemm<<<dim3(128, splits), 256, 0, stream>>>(A, Yt, P, splits);
  k_out<<<dim3(128, 2), 128, 0, stream>>>(P, Yrm, Wb, dis, b, out, splits);
}

// Round 2
// 509.758 us; speedup vs baseline: 1.0290x; 1.0290x over previous
//
#include <hip/hip_runtime.h>
#include <hip/hip_bf16.h>
#include <stdint.h>

#define NROW 8192
#define NCOL 8192
#define INF 256
#define OUTF 256

typedef __attribute__((ext_vector_type(4))) float f32x4;
typedef __attribute__((ext_vector_type(8))) short s16x8;
typedef __attribute__((ext_vector_type(4))) int i32x4;
typedef __attribute__((ext_vector_type(2))) unsigned int u32x2;

__device__ __forceinline__ short f2bf(float f) {
  unsigned int u = __builtin_bit_cast(unsigned int, f);
  unsigned int r = (u + 0x7FFFu + ((u >> 16) & 1u)) >> 16;  // RTNE
  return (short)r;
}
__device__ __forceinline__ float bf2f(short s) {
  unsigned int u = ((unsigned int)(unsigned short)s) << 16;
  return __builtin_bit_cast(float, u);
}
// packed fp32x2 -> bf16x2 (RTNE), single HW instruction
__device__ __forceinline__ unsigned int pkbf(float lo, float hi) {
#if __has_builtin(__builtin_amdgcn_cvt_pk_bf16_f32)
  auto t = __builtin_amdgcn_cvt_pk_bf16_f32(lo, hi);
  return __builtin_bit_cast(unsigned int, t);
#else
  unsigned int r;
  asm("v_cvt_pk_bf16_f32 %0, %1, %2" : "=v"(r) : "v"(lo), "v"(hi));
  return r;
#endif
}

// global fp32 16B-chunk -> LDS, async DMA (wave-uniform LDS base + lane*16)
#define GLDS(g, l)                                                            \
  __builtin_amdgcn_global_load_lds(                                           \
      (const __attribute__((address_space(1))) void*)(g),                     \
      (__attribute__((address_space(3))) void*)(l), 16, 0, 0)

// ---------------------------------------------------------------------------
// K1: dis[i] = 1/sqrt(1 + sum_j A[i,j]); one wave per row, 4 rows/block
// ---------------------------------------------------------------------------
__global__ __launch_bounds__(256) void k_deg(const float* __restrict__ A,
                                             float* __restrict__ dis) {
  const int wave = threadIdx.x >> 6, lane = threadIdx.x & 63;
  const int row = (blockIdx.x << 2) + wave;
  const f32x4* Ar = (const f32x4*)(A + (size_t)row * NCOL);
  float s = 0.f;
#pragma unroll 8
  for (int it = 0; it < 32; ++it) {
    f32x4 v = Ar[(it << 6) + lane];
    s += (v.x + v.y) + (v.z + v.w);
  }
#pragma unroll
  for (int off = 32; off > 0; off >>= 1) s += __shfl_down(s, off, 64);
  if (lane == 0) dis[row] = 1.0f / sqrtf(s + 1.0f);
}

// ---------------------------------------------------------------------------
// K2: Yt[f][j] = bf16(X[j][f]*dis[j]) (transposed, B-operand feed)
//     Yrm[j][f] = same, row-major (+I term);  Wb = bf16(W)
// ---------------------------------------------------------------------------
__global__ __launch_bounds__(256) void k_prep(const float* __restrict__ X,
                                              const float* __restrict__ W,
                                              const float* __restrict__ dis,
                                              short* __restrict__ Yt,
                                              short* __restrict__ Yrm,
                                              short* __restrict__ Wb) {
  __shared__ short T[256][72];
  __shared__ float sd[64];
  const int tid = threadIdx.x;

  if (blockIdx.x >= 128) {  // W convert
    const int idx8 = (((int)blockIdx.x - 128) * 256 + tid) << 3;
    f32x4 a = *(const f32x4*)(W + idx8);
    f32x4 b = *(const f32x4*)(W + idx8 + 4);
    i32x4 o;
    o.x = (int)pkbf(a.x, a.y); o.y = (int)pkbf(a.z, a.w);
    o.z = (int)pkbf(b.x, b.y); o.w = (int)pkbf(b.z, b.w);
    *(i32x4*)(Wb + idx8) = o;
    return;
  }

  const int jb = blockIdx.x << 6;
  if (tid < 64) sd[tid] = dis[jb + tid];
  __syncthreads();
#pragma unroll
  for (int i = 0; i < 16; ++i) {
    const int flat = (i << 8) + tid;
    const int j = flat >> 6;
    const int fc = flat & 63;
    f32x4 v = *(const f32x4*)(X + (size_t)(jb + j) * INF + (fc << 2));
    const float d = sd[j];
    short b0 = f2bf(v.x * d), b1 = f2bf(v.y * d);
    short b2 = f2bf(v.z * d), b3 = f2bf(v.w * d);
    T[(fc << 2) + 0][j] = b0;
    T[(fc << 2) + 1][j] = b1;
    T[(fc << 2) + 2][j] = b2;
    T[(fc << 2) + 3][j] = b3;
    u32x2 p;
    p.x = (unsigned int)(unsigned short)b0 | ((unsigned int)(unsigned short)b1 << 16);
    p.y = (unsigned int)(unsigned short)b2 | ((unsigned int)(unsigned short)b3 << 16);
    *(u32x2*)(Yrm + (size_t)(jb + j) * INF + (fc << 2)) = p;
  }
  __syncthreads();
#pragma unroll
  for (int c = 0; c < 8; ++c) {
    s16x8 v = *(const s16x8*)&T[tid][c << 3];
    *(s16x8*)(Yt + (size_t)tid * NROW + jb + (c << 3)) = v;
  }
}

// ---------------------------------------------------------------------------
// K3: P[sp] = A[64 rows, ksp] @ Yt^T  (bf16 MFMA, fp32 acc)
// BM=64 BN=256 BK=64; 2-buffer LDS (32 KB), distance-1 issue-after-barrier
// DMA (16 KB in flight per block -> MLP-saturated); B from L2/L3 with
// half-step register prefetch; packed bf16 converts.
// ---------------------------------------------------------------------------
__device__ __forceinline__ s16x8 ldcvt(const float* buf, int n, int kc, int lq) {
  const int base = (n << 6) + (kc << 5);
  const int sw = n & 7;
  f32x4 u0 = *(const f32x4*)(buf + base + ((((lq << 1) | 0) ^ sw) << 2));
  f32x4 u1 = *(const f32x4*)(buf + base + ((((lq << 1) | 1) ^ sw) << 2));
  i32x4 t;
  t.x = (int)pkbf(u0.x, u0.y);
  t.y = (int)pkbf(u0.z, u0.w);
  t.z = (int)pkbf(u1.x, u1.y);
  t.w = (int)pkbf(u1.z, u1.w);
  return __builtin_bit_cast(s16x8, t);
}

__global__ __launch_bounds__(256, 2) void k_gemm(const float* __restrict__ A,
                                                 const short* __restrict__ Yt,
                                                 float* __restrict__ P,
                                                 int splits) {
  __shared__ float Ab[2 * 4096];  // 2 x (64 rows x 64 floats), chunk-swizzled
  const int tid = threadIdx.x;
  const int w = tid >> 6, l = tid & 63, lr = l & 15, lq = l >> 4;
  const int row0 = (int)blockIdx.x << 6;
  const int sp = blockIdx.y;
  const int kspan = NCOL / splits;
  const int k0 = sp * kspan;
  const int steps = kspan >> 6;

  // DMA source addresses: chunk p = tid + j*256; n=p>>4 (row), h=(p>>3)&1,
  // cpos=p&7; global 16B chunk (within 32-float half) = cpos ^ (n&7)
  const char* gA[4];
#pragma unroll
  for (int j = 0; j < 4; ++j) {
    const int p = tid + (j << 8);
    const int n = p >> 4, h = (p >> 3) & 1, cpos = p & 7;
    const int c = cpos ^ (n & 7);
    gA[j] = (const char*)(A + (size_t)(row0 + n) * NCOL + k0 + (h << 5) + (c << 2));
  }
  char* ldst0 = (char*)Ab + ((tid & ~63) << 4);  // + j*4096 (+ lane*16 by HW)

  const short* Brow = Yt + (size_t)((w << 6) + lr) * NROW + k0 + (lq << 3);

  f32x4 acc[4][4];
#pragma unroll
  for (int rt = 0; rt < 4; ++rt)
#pragma unroll
    for (int ct = 0; ct < 4; ++ct) acc[rt][ct] = (f32x4){0.f, 0.f, 0.f, 0.f};

  // prologue: DMA(0) into buf0; prefetch B(0, kc=0)
#pragma unroll
  for (int j = 0; j < 4; ++j) GLDS(gA[j], ldst0 + (j << 12));
  i32x4 bB0[4];
#pragma unroll
  for (int ct = 0; ct < 4; ++ct)
    bB0[ct] = *(const i32x4*)(Brow + (size_t)(ct << 4) * NROW);

  for (int s = 0; s < steps; ++s) {
    __syncthreads();  // drains DMA(s) + B-prefetches for step s

    if (s + 1 < steps) {  // DMA(s+1) into the buffer read at step s-1
      char* dst = ldst0 + (((s + 1) & 1) << 14);
      const size_t go = (size_t)(s + 1) << 8;
#pragma unroll
      for (int j = 0; j < 4; ++j) GLDS(gA[j] + go, dst + (j << 12));
    }

    // issue B(s, kc=1) early; covered by kc=0 compute
    i32x4 bB1[4];
#pragma unroll
    for (int ct = 0; ct < 4; ++ct)
      bB1[ct] = *(const i32x4*)(Brow + (size_t)(ct << 4) * NROW +
                                ((size_t)s << 6) + 32);

    const float* buf = Ab + ((s & 1) << 12);

    // ---- kc = 0 ----
    s16x8 af[4];
#pragma unroll
    for (int rt = 0; rt < 4; ++rt) af[rt] = ldcvt(buf, (rt << 4) + lr, 0, lq);
#pragma unroll
    for (int rt = 0; rt < 4; ++rt) {
      const s16x8 a = af[rt];
#pragma unroll
      for (int ct = 0; ct < 4; ++ct)
        acc[rt][ct] = __builtin_amdgcn_mfma_f32_16x16x32_bf16(
            a, __builtin_bit_cast(s16x8, bB0[ct]), acc[rt][ct], 0, 0, 0);
    }

    if (s + 1 < steps) {  // prefetch B(s+1, kc=0)
#pragma unroll
      for (int ct = 0; ct < 4; ++ct)
        bB0[ct] = *(const i32x4*)(Brow + (size_t)(ct << 4) * NROW +
                                  ((size_t)(s + 1) << 6));
    }

    // ---- kc = 1 ----
#pragma unroll
    for (int rt = 0; rt < 4; ++rt) af[rt] = ldcvt(buf, (rt << 4) + lr, 1, lq);
#pragma unroll
    for (int rt = 0; rt < 4; ++rt) {
      const s16x8 a = af[rt];
#pragma unroll
      for (int ct = 0; ct < 4; ++ct)
        acc[rt][ct] = __builtin_amdgcn_mfma_f32_16x16x32_bf16(
            a, __builtin_bit_cast(s16x8, bB1[ct]), acc[rt][ct], 0, 0, 0);
    }
  }

  float* Pp = P + ((size_t)sp << 21);
#pragma unroll
  for (int rt = 0; rt < 4; ++rt)
#pragma unroll
    for (int ct = 0; ct < 4; ++ct) {
      const int col = (w << 6) + (ct << 4) + lr;
      const int row = row0 + (rt << 4) + (lq << 2);
#pragma unroll
      for (int r = 0; r < 4; ++r)
        Pp[((size_t)(row + r) << 8) + col] = acc[rt][ct][r];
    }
}

// ---------------------------------------------------------------------------
// K4: h = dis[i]*(sum_sp P + Yrm[i]); out = h @ Wb^T + b
// 16 rows x 256 cols per block, 4 waves x (16x64); 512 blocks (2/CU)
// ---------------------------------------------------------------------------
__global__ __launch_bounds__(256) void k_out(const float* __restrict__ P,
                                             const short* __restrict__ Yrm,
                                             const short* __restrict__ Wb,
                                             const float* __restrict__ dis,
                                             const float* __restrict__ bias,
                                             float* __restrict__ out,
                                             int splits) {
  const int w = threadIdx.x >> 6, l = threadIdx.x & 63, lr = l & 15, lq = l >> 4;
  const int row0 = (int)blockIdx.x << 4;
  const int col0 = w << 6;
  const int row = row0 + lr;
  const float di = dis[row];

  f32x4 acc[4];
#pragma unroll
  for (int ct = 0; ct < 4; ++ct) acc[ct] = (f32x4){0.f, 0.f, 0.f, 0.f};

  for (int s = 0; s < 8; ++s) {
    const int f0 = (s << 5) + (lq << 3);
    s16x8 wf[4];
#pragma unroll
    for (int ct = 0; ct < 4; ++ct)
      wf[ct] = *(const s16x8*)(Wb + ((size_t)(col0 + (ct << 4) + lr) << 8) + f0);

    const float* p = P + ((size_t)row << 8) + f0;
    f32x4 u0 = *(const f32x4*)(p);
    f32x4 u1 = *(const f32x4*)(p + 4);
    for (int sp = 1; sp < splits; ++sp) {
      const float* q = p + ((size_t)sp << 21);
      u0 += *(const f32x4*)(q);
      u1 += *(const f32x4*)(q + 4);
    }
    s16x8 y = *(const s16x8*)(Yrm + ((size_t)row << 8) + f0);
    i32x4 t;
    t.x = (int)pkbf((u0.x + bf2f(y[0])) * di, (u0.y + bf2f(y[1])) * di);
    t.y = (int)pkbf((u0.z + bf2f(y[2])) * di, (u0.w + bf2f(y[3])) * di);
    t.z = (int)pkbf((u1.x + bf2f(y[4])) * di, (u1.y + bf2f(y[5])) * di);
    t.w = (int)pkbf((u1.z + bf2f(y[6])) * di, (u1.w + bf2f(y[7])) * di);
    const s16x8 af = __builtin_bit_cast(s16x8, t);
#pragma unroll
    for (int ct = 0; ct < 4; ++ct)
      acc[ct] = __builtin_amdgcn_mfma_f32_16x16x32_bf16(af, wf[ct], acc[ct],
                                                        0, 0, 0);
  }

#pragma unroll
  for (int ct = 0; ct < 4; ++ct) {
    const int col = col0 + (ct << 4) + lr;
    const float bb = bias[col];
#pragma unroll
    for (int r = 0; r < 4; ++r)
      out[((size_t)(row0 + (lq << 2) + r) << 8) + col] = acc[ct][r] + bb;
  }
}

// ---------------------------------------------------------------------------
extern "C" void kernel_launch(void* const* d_in, const int* in_sizes, int n_in,
                              void* d_out, int out_size, void* d_ws,
                              size_t ws_size, hipStream_t stream) {
  const float* X = (const float*)d_in[0];
  const float* A = (const float*)d_in[1];
  const float* W = (const float*)d_in[2];
  const float* b = (const float*)d_in[3];
  float* out = (float*)d_out;

  char* ws = (char*)d_ws;
  float* dis = (float*)ws;                          // 32 KB
  short* Yt  = (short*)(ws + 32768);                // 4 MB
  short* Yrm = (short*)(ws + 32768 + 4194304);      // 4 MB
  short* Wb  = (short*)(ws + 32768 + 2 * 4194304);  // 128 KB
  const size_t base = 32768 + 2ull * 4194304 + 131072;
  float* P = (float*)(ws + base);                   // splits * 8 MB

  const int splits = (ws_size >= base + 8ull * 8388608) ? 8 : 4;

  k_deg<<<2048, 256, 0, stream>>>(A, dis);
  k_prep<<<160, 256, 0, stream>>>(X, W, dis, Yt, Yrm, Wb);
  k_gemm<<<dim3(128, splits), 256, 0, stream>>>(A, Yt, P, splits);
  k_out<<<512, 256, 0, stream>>>(P, Yrm, Wb, dis, b, out, splits);
}

// Round 4
// 459.424 us; speedup vs baseline: 1.1417x; 1.1096x over previous
//
#include <hip/hip_runtime.h>
#include <hip/hip_bf16.h>
#include <stdint.h>

#define NROW 8192
#define NCOL 8192
#define INF 256
#define OUTF 256

typedef __attribute__((ext_vector_type(4))) float f32x4;
typedef __attribute__((ext_vector_type(8))) short s16x8;
typedef __attribute__((ext_vector_type(4))) int i32x4;
typedef __attribute__((ext_vector_type(2))) unsigned int u32x2;

__device__ __forceinline__ short f2bf(float f) {
  unsigned int u = __builtin_bit_cast(unsigned int, f);
  unsigned int r = (u + 0x7FFFu + ((u >> 16) & 1u)) >> 16;  // RTNE
  return (short)r;
}
__device__ __forceinline__ float bf2f(short s) {
  unsigned int u = ((unsigned int)(unsigned short)s) << 16;
  return __builtin_bit_cast(float, u);
}
__device__ __forceinline__ unsigned int pkbf(float lo, float hi) {
#if __has_builtin(__builtin_amdgcn_cvt_pk_bf16_f32)
  auto t = __builtin_amdgcn_cvt_pk_bf16_f32(lo, hi);
  return __builtin_bit_cast(unsigned int, t);
#else
  unsigned int r;
  asm("v_cvt_pk_bf16_f32 %0, %1, %2" : "=v"(r) : "v"(lo), "v"(hi));
  return r;
#endif
}

#define GLDS(g, l)                                                            \
  __builtin_amdgcn_global_load_lds(                                           \
      (const __attribute__((address_space(1))) void*)(g),                     \
      (__attribute__((address_space(3))) void*)(l), 16, 0, 0)

// ---------------------------------------------------------------------------
// K1: dis[i] = 1/sqrt(1 + sum_j A[i,j]); one wave per row, 4 rows/block
// ---------------------------------------------------------------------------
__global__ __launch_bounds__(256) void k_deg(const float* __restrict__ A,
                                             float* __restrict__ dis) {
  const int wave = threadIdx.x >> 6, lane = threadIdx.x & 63;
  const int row = (blockIdx.x << 2) + wave;
  const f32x4* Ar = (const f32x4*)(A + (size_t)row * NCOL);
  float s = 0.f;
#pragma unroll 8
  for (int it = 0; it < 32; ++it) {
    f32x4 v = Ar[(it << 6) + lane];
    s += (v.x + v.y) + (v.z + v.w);
  }
#pragma unroll
  for (int off = 32; off > 0; off >>= 1) s += __shfl_down(s, off, 64);
  if (lane == 0) dis[row] = 1.0f / sqrtf(s + 1.0f);
}

// ---------------------------------------------------------------------------
// K2: Ytf = bf16(X^T * d) in MFMA-B FRAGMENT ORDER:
//   frag (ftile=f>>4, kb=j>>5) is 512 contiguous shorts;
//   pos = lane*8 + elem, lane = (f&15) + 16*((j&31)>>3), elem = j&7.
//   => k_gemm B-loads are single coalesced 1KB wave-loads (no row gather).
// Yrm[j][f] = bf16(X[j][f]*d[j]) row-major (+I term).
// Wbf = bf16(W) in the same fragment order over (out_f, in_f).
// ---------------------------------------------------------------------------
__global__ __launch_bounds__(256) void k_prep(const float* __restrict__ X,
                                              const float* __restrict__ W,
                                              const float* __restrict__ dis,
                                              short* __restrict__ Ytf,
                                              short* __restrict__ Yrm,
                                              short* __restrict__ Wbf) {
  __shared__ short T[256][72];  // [f][j-local], 144B rows (16B aligned)
  __shared__ float sd[64];
  const int tid = threadIdx.x;

  if (blockIdx.x >= 128) {  // W convert, frag-ordered
    const int idx8 = (((int)blockIdx.x - 128) * 256 + tid) << 3;
    const int o = idx8 >> 8, k = idx8 & 255;  // 8 consecutive k, k%8==0
    f32x4 a = *(const f32x4*)(W + idx8);
    f32x4 b = *(const f32x4*)(W + idx8 + 4);
    i32x4 v;
    v.x = (int)pkbf(a.x, a.y); v.y = (int)pkbf(a.z, a.w);
    v.z = (int)pkbf(b.x, b.y); v.w = (int)pkbf(b.z, b.w);
    // frag = (o>>4)*8 + (k>>5); lane = (o&15) + 16*((k&31)>>3); elem = 0
    const int dst = (((o >> 4) << 3) + (k >> 5)) * 512 +
                    ((o & 15) << 3) + (((k & 31) >> 3) << 7);
    *(i32x4*)(Wbf + dst) = v;
    return;
  }

  const int jb = blockIdx.x << 6;
  if (tid < 64) sd[tid] = dis[jb + tid];
  __syncthreads();
#pragma unroll
  for (int i = 0; i < 16; ++i) {
    const int flat = (i << 8) + tid;
    const int j = flat >> 6;
    const int fc = flat & 63;
    f32x4 v = *(const f32x4*)(X + (size_t)(jb + j) * INF + (fc << 2));
    const float d = sd[j];
    short b0 = f2bf(v.x * d), b1 = f2bf(v.y * d);
    short b2 = f2bf(v.z * d), b3 = f2bf(v.w * d);
    T[(fc << 2) + 0][j] = b0;
    T[(fc << 2) + 1][j] = b1;
    T[(fc << 2) + 2][j] = b2;
    T[(fc << 2) + 3][j] = b3;
    u32x2 p;
    p.x = (unsigned int)(unsigned short)b0 | ((unsigned int)(unsigned short)b1 << 16);
    p.y = (unsigned int)(unsigned short)b2 | ((unsigned int)(unsigned short)b3 << 16);
    *(u32x2*)(Yrm + (size_t)(jb + j) * INF + (fc << 2)) = p;
  }
  __syncthreads();
  // writer: thread tid = f; 8 chunks of 8 j's, each one 16B store, frag order
  const int f = tid;
#pragma unroll
  for (int c = 0; c < 8; ++c) {
    s16x8 v = *(const s16x8*)&T[f][c << 3];
    const int j = jb + (c << 3);
    const size_t dst = ((size_t)(((f >> 4) << 8) + (j >> 5)) << 9) +
                       (((f & 15) + (((j & 31) >> 3) << 4)) << 3);
    *(s16x8*)(Ytf + dst) = v;
  }
}

// ---------------------------------------------------------------------------
// K3: P[sp] = A[64 rows, ksp] @ Yt^T  (bf16 MFMA, fp32 acc)
// BM=64 BN=256 BK=64; A via GLDS into 2-buffer swizzled LDS;
// B via COALESCED frag-ordered loads from L2-resident Ytf.
// ---------------------------------------------------------------------------
__device__ __forceinline__ s16x8 ldcvt(const float* buf, int n, int kc, int lq) {
  const int base = (n << 6) + (kc << 5);
  const int sw = n & 7;
  f32x4 u0 = *(const f32x4*)(buf + base + ((((lq << 1) | 0) ^ sw) << 2));
  f32x4 u1 = *(const f32x4*)(buf + base + ((((lq << 1) | 1) ^ sw) << 2));
  i32x4 t;
  t.x = (int)pkbf(u0.x, u0.y);
  t.y = (int)pkbf(u0.z, u0.w);
  t.z = (int)pkbf(u1.x, u1.y);
  t.w = (int)pkbf(u1.z, u1.w);
  return __builtin_bit_cast(s16x8, t);
}

__global__ __launch_bounds__(256, 2) void k_gemm(const float* __restrict__ A,
                                                 const short* __restrict__ Ytf,
                                                 float* __restrict__ P,
                                                 int splits) {
  __shared__ float Ab[2 * 4096];  // 2 x (64 rows x 64 floats), chunk-swizzled
  const int tid = threadIdx.x;
  const int w = tid >> 6, l = tid & 63, lr = l & 15, lq = l >> 4;
  const int row0 = (int)blockIdx.x << 6;
  const int sp = blockIdx.y;
  const int kspan = NCOL / splits;
  const int k0 = sp * kspan;
  const int steps = kspan >> 6;

  const char* gA[4];
#pragma unroll
  for (int j = 0; j < 4; ++j) {
    const int p = tid + (j << 8);
    const int n = p >> 4, h = (p >> 3) & 1, cpos = p & 7;
    const int c = cpos ^ (n & 7);
    gA[j] = (const char*)(A + (size_t)(row0 + n) * NCOL + k0 + (h << 5) + (c << 2));
  }
  char* ldst0 = (char*)Ab + ((tid & ~63) << 4);

  // frag-ordered B: frag (ftile = w*4+ct, kb) at Ytf[(ftile*256+kb)*512 + l*8]
  const short* Bw = Ytf + ((size_t)w << 19) + ((size_t)(k0 >> 5) << 9) + (l << 3);

  f32x4 acc[4][4];
#pragma unroll
  for (int rt = 0; rt < 4; ++rt)
#pragma unroll
    for (int ct = 0; ct < 4; ++ct) acc[rt][ct] = (f32x4){0.f, 0.f, 0.f, 0.f};

  // prologue: DMA(0); B(0, kc=0)
#pragma unroll
  for (int j = 0; j < 4; ++j) GLDS(gA[j], ldst0 + (j << 12));
  i32x4 bB0[4];
#pragma unroll
  for (int ct = 0; ct < 4; ++ct)
    bB0[ct] = *(const i32x4*)(Bw + ((size_t)ct << 17));

  for (int s = 0; s < steps; ++s) {
    __syncthreads();  // drains DMA(s) + B-prefetches for step s

    if (s + 1 < steps) {
      char* dst = ldst0 + (((s + 1) & 1) << 14);
      const size_t go = (size_t)(s + 1) << 8;  // 256 B = 64 floats
#pragma unroll
      for (int j = 0; j < 4; ++j) GLDS(gA[j] + go, dst + (j << 12));
    }

    // B(s, kc=1), coalesced
    i32x4 bB1[4];
#pragma unroll
    for (int ct = 0; ct < 4; ++ct)
      bB1[ct] = *(const i32x4*)(Bw + ((size_t)ct << 17) +
                                ((size_t)((s << 1) + 1) << 9));

    const float* buf = Ab + ((s & 1) << 12);

    // ---- kc = 0 ----
    s16x8 af[4];
#pragma unroll
    for (int rt = 0; rt < 4; ++rt) af[rt] = ldcvt(buf, (rt << 4) + lr, 0, lq);
#pragma unroll
    for (int rt = 0; rt < 4; ++rt) {
      const s16x8 a = af[rt];
#pragma unroll
      for (int ct = 0; ct < 4; ++ct)
        acc[rt][ct] = __builtin_amdgcn_mfma_f32_16x16x32_bf16(
            a, __builtin_bit_cast(s16x8, bB0[ct]), acc[rt][ct], 0, 0, 0);
    }

    if (s + 1 < steps) {  // prefetch B(s+1, kc=0)
#pragma unroll
      for (int ct = 0; ct < 4; ++ct)
        bB0[ct] = *(const i32x4*)(Bw + ((size_t)ct << 17) +
                                  ((size_t)((s << 1) + 2) << 9));
    }

    // ---- kc = 1 ----
#pragma unroll
    for (int rt = 0; rt < 4; ++rt) af[rt] = ldcvt(buf, (rt << 4) + lr, 1, lq);
#pragma unroll
    for (int rt = 0; rt < 4; ++rt) {
      const s16x8 a = af[rt];
#pragma unroll
      for (int ct = 0; ct < 4; ++ct)
        acc[rt][ct] = __builtin_amdgcn_mfma_f32_16x16x32_bf16(
            a, __builtin_bit_cast(s16x8, bB1[ct]), acc[rt][ct], 0, 0, 0);
    }
  }

  float* Pp = P + ((size_t)sp << 21);
#pragma unroll
  for (int rt = 0; rt < 4; ++rt)
#pragma unroll
    for (int ct = 0; ct < 4; ++ct) {
      const int col = (w << 6) + (ct << 4) + lr;
      const int row = row0 + (rt << 4) + (lq << 2);
#pragma unroll
      for (int r = 0; r < 4; ++r)
        Pp[((size_t)(row + r) << 8) + col] = acc[rt][ct][r];
    }
}

// ---------------------------------------------------------------------------
// K4: h = dis[i]*(sum_sp P + Yrm[i]); out = h @ Wb^T + b
// 16 rows x 256 cols per block, 4 waves; Wbf frag-ordered (coalesced)
// ---------------------------------------------------------------------------
__global__ __launch_bounds__(256) void k_out(const float* __restrict__ P,
                                             const short* __restrict__ Yrm,
                                             const short* __restrict__ Wbf,
                                             const float* __restrict__ dis,
                                             const float* __restrict__ bias,
                                             float* __restrict__ out,
                                             int splits) {
  const int w = threadIdx.x >> 6, l = threadIdx.x & 63, lr = l & 15, lq = l >> 4;
  const int row0 = (int)blockIdx.x << 4;
  const int col0 = w << 6;
  const int row = row0 + lr;
  const float di = dis[row];

  // frag-ordered W: frag (ftile = w*4+ct, kb = s) at Wbf[(ftile*8+s)*512+l*8]
  const short* Ww = Wbf + ((size_t)w << 14) + (l << 3);

  f32x4 acc[4];
#pragma unroll
  for (int ct = 0; ct < 4; ++ct) acc[ct] = (f32x4){0.f, 0.f, 0.f, 0.f};

  for (int s = 0; s < 8; ++s) {
    const int f0 = (s << 5) + (lq << 3);
    s16x8 wf[4];
#pragma unroll
    for (int ct = 0; ct < 4; ++ct)
      wf[ct] = *(const s16x8*)(Ww + (ct << 12) + (s << 9));

    const float* p = P + ((size_t)row << 8) + f0;
    f32x4 u0 = *(const f32x4*)(p);
    f32x4 u1 = *(const f32x4*)(p + 4);
    for (int sp = 1; sp < splits; ++sp) {
      const float* q = p + ((size_t)sp << 21);
      u0 += *(const f32x4*)(q);
      u1 += *(const f32x4*)(q + 4);
    }
    s16x8 y = *(const s16x8*)(Yrm + ((size_t)row << 8) + f0);
    i32x4 t;
    t.x = (int)pkbf((u0.x + bf2f(y[0])) * di, (u0.y + bf2f(y[1])) * di);
    t.y = (int)pkbf((u0.z + bf2f(y[2])) * di, (u0.w + bf2f(y[3])) * di);
    t.z = (int)pkbf((u1.x + bf2f(y[4])) * di, (u1.y + bf2f(y[5])) * di);
    t.w = (int)pkbf((u1.z + bf2f(y[6])) * di, (u1.w + bf2f(y[7])) * di);
    const s16x8 af = __builtin_bit_cast(s16x8, t);
#pragma unroll
    for (int ct = 0; ct < 4; ++ct)
      acc[ct] = __builtin_amdgcn_mfma_f32_16x16x32_bf16(af, wf[ct], acc[ct],
                                                        0, 0, 0);
  }

#pragma unroll
  for (int ct = 0; ct < 4; ++ct) {
    const int col = col0 + (ct << 4) + lr;
    const float bb = bias[col];
#pragma unroll
    for (int r = 0; r < 4; ++r)
      out[((size_t)(row0 + (lq << 2) + r) << 8) + col] = acc[ct][r] + bb;
  }
}

// ---------------------------------------------------------------------------
extern "C" void kernel_launch(void* const* d_in, const int* in_sizes, int n_in,
                              void* d_out, int out_size, void* d_ws,
                              size_t ws_size, hipStream_t stream) {
  const float* X = (const float*)d_in[0];
  const float* A = (const float*)d_in[1];
  const float* W = (const float*)d_in[2];
  const float* b = (const float*)d_in[3];
  float* out = (float*)d_out;

  char* ws = (char*)d_ws;
  float* dis = (float*)ws;                          // 32 KB
  short* Ytf = (short*)(ws + 32768);                // 4 MB (frag-ordered)
  short* Yrm = (short*)(ws + 32768 + 4194304);      // 4 MB
  short* Wbf = (short*)(ws + 32768 + 2 * 4194304);  // 128 KB (frag-ordered)
  const size_t base = 32768 + 2ull * 4194304 + 131072;
  float* P = (float*)(ws + base);                   // splits * 8 MB

  const int splits = (ws_size >= base + 4ull * 8388608) ? 4 : 1;

  k_deg<<<2048, 256, 0, stream>>>(A, dis);
  k_prep<<<160, 256, 0, stream>>>(X, W, dis, Ytf, Yrm, Wbf);
  k_gemm<<<dim3(128, splits), 256, 0, stream>>>(A, Ytf, P, splits);
  k_out<<<512, 256, 0, stream>>>(P, Yrm, Wbf, dis, b, out, splits);
}

// Round 5
// 457.930 us; speedup vs baseline: 1.1454x; 1.0033x over previous
//
#include <hip/hip_runtime.h>
#include <hip/hip_bf16.h>
#include <stdint.h>

#define NROW 8192
#define NCOL 8192
#define INF 256
#define OUTF 256

typedef __attribute__((ext_vector_type(4))) float f32x4;
typedef __attribute__((ext_vector_type(8))) short s16x8;
typedef __attribute__((ext_vector_type(4))) int i32x4;
typedef __attribute__((ext_vector_type(2))) unsigned int u32x2;

__device__ __forceinline__ short f2bf(float f) {
  unsigned int u = __builtin_bit_cast(unsigned int, f);
  unsigned int r = (u + 0x7FFFu + ((u >> 16) & 1u)) >> 16;  // RTNE
  return (short)r;
}
__device__ __forceinline__ float bf2f(short s) {
  unsigned int u = ((unsigned int)(unsigned short)s) << 16;
  return __builtin_bit_cast(float, u);
}
__device__ __forceinline__ unsigned int pkbf(float lo, float hi) {
#if __has_builtin(__builtin_amdgcn_cvt_pk_bf16_f32)
  auto t = __builtin_amdgcn_cvt_pk_bf16_f32(lo, hi);
  return __builtin_bit_cast(unsigned int, t);
#else
  unsigned int r;
  asm("v_cvt_pk_bf16_f32 %0, %1, %2" : "=v"(r) : "v"(lo), "v"(hi));
  return r;
#endif
}

#define GLDS(g, l)                                                            \
  __builtin_amdgcn_global_load_lds(                                           \
      (const __attribute__((address_space(1))) void*)(g),                     \
      (__attribute__((address_space(3))) void*)(l), 16, 0, 0)

// ---------------------------------------------------------------------------
// K1: dis[i] = 1/sqrt(1 + sum_j A[i,j]); one wave per row, 4 rows/block
// ---------------------------------------------------------------------------
__global__ __launch_bounds__(256) void k_deg(const float* __restrict__ A,
                                             float* __restrict__ dis) {
  const int wave = threadIdx.x >> 6, lane = threadIdx.x & 63;
  const int row = (blockIdx.x << 2) + wave;
  const f32x4* Ar = (const f32x4*)(A + (size_t)row * NCOL);
  float s = 0.f;
#pragma unroll 8
  for (int it = 0; it < 32; ++it) {
    f32x4 v = Ar[(it << 6) + lane];
    s += (v.x + v.y) + (v.z + v.w);
  }
#pragma unroll
  for (int off = 32; off > 0; off >>= 1) s += __shfl_down(s, off, 64);
  if (lane == 0) dis[row] = 1.0f / sqrtf(s + 1.0f);
}

// ---------------------------------------------------------------------------
// K2: Ytf = bf16(X^T * d) in MFMA-B FRAGMENT ORDER:
//   frag (ftile=f>>4, kb=j>>5) is 512 contiguous shorts;
//   pos = lane*8 + elem, lane = (f&15) + 16*((j&31)>>3), elem = j&7.
// Yrm[j][f] = bf16(X[j][f]*d[j]) row-major (+I term).
// Wbf = bf16(W) in the same fragment order over (out_f, in_f).
// ---------------------------------------------------------------------------
__global__ __launch_bounds__(256) void k_prep(const float* __restrict__ X,
                                              const float* __restrict__ W,
                                              const float* __restrict__ dis,
                                              short* __restrict__ Ytf,
                                              short* __restrict__ Yrm,
                                              short* __restrict__ Wbf) {
  __shared__ short T[256][72];  // [f][j-local], 144B rows (16B aligned)
  __shared__ float sd[64];
  const int tid = threadIdx.x;

  if (blockIdx.x >= 128) {  // W convert, frag-ordered
    const int idx8 = (((int)blockIdx.x - 128) * 256 + tid) << 3;
    const int o = idx8 >> 8, k = idx8 & 255;  // 8 consecutive k, k%8==0
    f32x4 a = *(const f32x4*)(W + idx8);
    f32x4 b = *(const f32x4*)(W + idx8 + 4);
    i32x4 v;
    v.x = (int)pkbf(a.x, a.y); v.y = (int)pkbf(a.z, a.w);
    v.z = (int)pkbf(b.x, b.y); v.w = (int)pkbf(b.z, b.w);
    // frag = (o>>4)*8 + (k>>5); lane = (o&15) + 16*((k&31)>>3); elem = 0
    const int dst = (((o >> 4) << 3) + (k >> 5)) * 512 +
                    ((o & 15) << 3) + (((k & 31) >> 3) << 7);
    *(i32x4*)(Wbf + dst) = v;
    return;
  }

  const int jb = blockIdx.x << 6;
  if (tid < 64) sd[tid] = dis[jb + tid];
  __syncthreads();
#pragma unroll
  for (int i = 0; i < 16; ++i) {
    const int flat = (i << 8) + tid;
    const int j = flat >> 6;
    const int fc = flat & 63;
    f32x4 v = *(const f32x4*)(X + (size_t)(jb + j) * INF + (fc << 2));
    const float d = sd[j];
    short b0 = f2bf(v.x * d), b1 = f2bf(v.y * d);
    short b2 = f2bf(v.z * d), b3 = f2bf(v.w * d);
    T[(fc << 2) + 0][j] = b0;
    T[(fc << 2) + 1][j] = b1;
    T[(fc << 2) + 2][j] = b2;
    T[(fc << 2) + 3][j] = b3;
    u32x2 p;
    p.x = (unsigned int)(unsigned short)b0 | ((unsigned int)(unsigned short)b1 << 16);
    p.y = (unsigned int)(unsigned short)b2 | ((unsigned int)(unsigned short)b3 << 16);
    *(u32x2*)(Yrm + (size_t)(jb + j) * INF + (fc << 2)) = p;
  }
  __syncthreads();
  const int f = tid;
#pragma unroll
  for (int c = 0; c < 8; ++c) {
    s16x8 v = *(const s16x8*)&T[f][c << 3];
    const int j = jb + (c << 3);
    const size_t dst = ((size_t)(((f >> 4) << 8) + (j >> 5)) << 9) +
                       (((f & 15) + (((j & 31) >> 3) << 4)) << 3);
    *(s16x8*)(Ytf + dst) = v;
  }
}

// ---------------------------------------------------------------------------
// K3: P[sp] = A[128 rows, ksp] @ Yt^T  (bf16 MFMA, fp32 acc)
// BM=128 BN=256 BK=64; 512 thr (8 waves: rw=w>>2 row-half, cw=w&3 col-strip,
// each wave 64x64). A via GLDS into 2-buffer swizzled LDS (2x32KB);
// B via coalesced frag-ordered loads from Ytf (traffic halved vs BM=64).
// ---------------------------------------------------------------------------
__device__ __forceinline__ s16x8 ldcvt(const float* buf, int n, int kc, int lq) {
  const int base = (n << 6) + (kc << 5);
  const int sw = n & 7;
  f32x4 u0 = *(const f32x4*)(buf + base + ((((lq << 1) | 0) ^ sw) << 2));
  f32x4 u1 = *(const f32x4*)(buf + base + ((((lq << 1) | 1) ^ sw) << 2));
  i32x4 t;
  t.x = (int)pkbf(u0.x, u0.y);
  t.y = (int)pkbf(u0.z, u0.w);
  t.z = (int)pkbf(u1.x, u1.y);
  t.w = (int)pkbf(u1.z, u1.w);
  return __builtin_bit_cast(s16x8, t);
}

__global__ __launch_bounds__(512, 4) void k_gemm(const float* __restrict__ A,
                                                 const short* __restrict__ Ytf,
                                                 float* __restrict__ P,
                                                 int splits) {
  __shared__ float Ab[2 * 8192];  // 2 x (128 rows x 64 floats), chunk-swizzled
  const int tid = threadIdx.x;
  const int w = tid >> 6, l = tid & 63, lr = l & 15, lq = l >> 4;
  const int cw = w & 3, rw = w >> 2;
  const int row0 = (int)blockIdx.x << 7;
  const int sp = blockIdx.y;
  const int kspan = NCOL / splits;
  const int k0 = sp * kspan;
  const int steps = kspan >> 6;
  const int nbase = rw << 6;

  // DMA sources: chunk p = tid + j*512 (j=0..3); n=p>>4 (row 0..127),
  // h=(p>>3)&1 (32-float half), cpos=p&7; global chunk c = cpos^(n&7)
  const char* gA[4];
#pragma unroll
  for (int j = 0; j < 4; ++j) {
    const int p = tid + (j << 9);
    const int n = p >> 4, h = (p >> 3) & 1, cpos = p & 7;
    const int c = cpos ^ (n & 7);
    gA[j] = (const char*)(A + (size_t)(row0 + n) * NCOL + k0 + (h << 5) + (c << 2));
  }
  char* ldst0 = (char*)Ab + ((tid & ~63) << 4);  // + j*8192 B (+ lane*16 by HW)

  // frag-ordered B: frag (ftile = cw*4+ct, kb) at Ytf[(ftile*256+kb)*512+l*8]
  const short* Bw = Ytf + ((size_t)cw << 19) + ((size_t)(k0 >> 5) << 9) + (l << 3);

  f32x4 acc[4][4];
#pragma unroll
  for (int rt = 0; rt < 4; ++rt)
#pragma unroll
    for (int ct = 0; ct < 4; ++ct) acc[rt][ct] = (f32x4){0.f, 0.f, 0.f, 0.f};

  // prologue: DMA(0); B(0, kc=0)
#pragma unroll
  for (int j = 0; j < 4; ++j) GLDS(gA[j], ldst0 + (j << 13));
  i32x4 bB0[4];
#pragma unroll
  for (int ct = 0; ct < 4; ++ct)
    bB0[ct] = *(const i32x4*)(Bw + ((size_t)ct << 17));

  for (int s = 0; s < steps; ++s) {
    __syncthreads();  // drains DMA(s) + B-prefetches for step s

    if (s + 1 < steps) {
      char* dst = ldst0 + (((s + 1) & 1) << 15);
      const size_t go = (size_t)(s + 1) << 8;  // 256 B = 64 floats
#pragma unroll
      for (int j = 0; j < 4; ++j) GLDS(gA[j] + go, dst + (j << 13));
    }

    // B(s, kc=1), coalesced, issued early (latency covered by kc=0 compute)
    i32x4 bB1[4];
#pragma unroll
    for (int ct = 0; ct < 4; ++ct)
      bB1[ct] = *(const i32x4*)(Bw + ((size_t)ct << 17) +
                                ((size_t)((s << 1) + 1) << 9));

    const float* buf = Ab + ((s & 1) << 13);

    // ---- kc = 0 ----
    s16x8 af[4];
#pragma unroll
    for (int rt = 0; rt < 4; ++rt)
      af[rt] = ldcvt(buf, nbase + (rt << 4) + lr, 0, lq);
#pragma unroll
    for (int rt = 0; rt < 4; ++rt) {
      const s16x8 a = af[rt];
#pragma unroll
      for (int ct = 0; ct < 4; ++ct)
        acc[rt][ct] = __builtin_amdgcn_mfma_f32_16x16x32_bf16(
            a, __builtin_bit_cast(s16x8, bB0[ct]), acc[rt][ct], 0, 0, 0);
    }

    if (s + 1 < steps) {  // prefetch B(s+1, kc=0)
#pragma unroll
      for (int ct = 0; ct < 4; ++ct)
        bB0[ct] = *(const i32x4*)(Bw + ((size_t)ct << 17) +
                                  ((size_t)((s << 1) + 2) << 9));
    }

    // ---- kc = 1 ----
#pragma unroll
    for (int rt = 0; rt < 4; ++rt)
      af[rt] = ldcvt(buf, nbase + (rt << 4) + lr, 1, lq);
#pragma unroll
    for (int rt = 0; rt < 4; ++rt) {
      const s16x8 a = af[rt];
#pragma unroll
      for (int ct = 0; ct < 4; ++ct)
        acc[rt][ct] = __builtin_amdgcn_mfma_f32_16x16x32_bf16(
            a, __builtin_bit_cast(s16x8, bB1[ct]), acc[rt][ct], 0, 0, 0);
    }
  }

  float* Pp = P + ((size_t)sp << 21);
#pragma unroll
  for (int rt = 0; rt < 4; ++rt)
#pragma unroll
    for (int ct = 0; ct < 4; ++ct) {
      const int col = (cw << 6) + (ct << 4) + lr;
      const int row = row0 + (rw << 6) + (rt << 4) + (lq << 2);
#pragma unroll
      for (int r = 0; r < 4; ++r)
        Pp[((size_t)(row + r) << 8) + col] = acc[rt][ct][r];
    }
}

// ---------------------------------------------------------------------------
// K4: h = dis[i]*(sum_sp P + Yrm[i]); out = h @ Wb^T + b
// 16 rows x 256 cols per block, 4 waves; Wbf frag-ordered (coalesced)
// ---------------------------------------------------------------------------
__global__ __launch_bounds__(256) void k_out(const float* __restrict__ P,
                                             const short* __restrict__ Yrm,
                                             const short* __restrict__ Wbf,
                                             const float* __restrict__ dis,
                                             const float* __restrict__ bias,
                                             float* __restrict__ out,
                                             int splits) {
  const int w = threadIdx.x >> 6, l = threadIdx.x & 63, lr = l & 15, lq = l >> 4;
  const int row0 = (int)blockIdx.x << 4;
  const int col0 = w << 6;
  const int row = row0 + lr;
  const float di = dis[row];

  const short* Ww = Wbf + ((size_t)w << 14) + (l << 3);

  f32x4 acc[4];
#pragma unroll
  for (int ct = 0; ct < 4; ++ct) acc[ct] = (f32x4){0.f, 0.f, 0.f, 0.f};

  for (int s = 0; s < 8; ++s) {
    const int f0 = (s << 5) + (lq << 3);
    s16x8 wf[4];
#pragma unroll
    for (int ct = 0; ct < 4; ++ct)
      wf[ct] = *(const s16x8*)(Ww + (ct << 12) + (s << 9));

    const float* p = P + ((size_t)row << 8) + f0;
    f32x4 u0 = *(const f32x4*)(p);
    f32x4 u1 = *(const f32x4*)(p + 4);
#pragma unroll 3
    for (int sp = 1; sp < splits; ++sp) {
      const float* q = p + ((size_t)sp << 21);
      u0 += *(const f32x4*)(q);
      u1 += *(const f32x4*)(q + 4);
    }
    s16x8 y = *(const s16x8*)(Yrm + ((size_t)row << 8) + f0);
    i32x4 t;
    t.x = (int)pkbf((u0.x + bf2f(y[0])) * di, (u0.y + bf2f(y[1])) * di);
    t.y = (int)pkbf((u0.z + bf2f(y[2])) * di, (u0.w + bf2f(y[3])) * di);
    t.z = (int)pkbf((u1.x + bf2f(y[4])) * di, (u1.y + bf2f(y[5])) * di);
    t.w = (int)pkbf((u1.z + bf2f(y[6])) * di, (u1.w + bf2f(y[7])) * di);
    const s16x8 af = __builtin_bit_cast(s16x8, t);
#pragma unroll
    for (int ct = 0; ct < 4; ++ct)
      acc[ct] = __builtin_amdgcn_mfma_f32_16x16x32_bf16(af, wf[ct], acc[ct],
                                                        0, 0, 0);
  }

#pragma unroll
  for (int ct = 0; ct < 4; ++ct) {
    const int col = col0 + (ct << 4) + lr;
    const float bb = bias[col];
#pragma unroll
    for (int r = 0; r < 4; ++r)
      out[((size_t)(row0 + (lq << 2) + r) << 8) + col] = acc[ct][r] + bb;
  }
}

// ---------------------------------------------------------------------------
extern "C" void kernel_launch(void* const* d_in, const int* in_sizes, int n_in,
                              void* d_out, int out_size, void* d_ws,
                              size_t ws_size, hipStream_t stream) {
  const float* X = (const float*)d_in[0];
  const float* A = (const float*)d_in[1];
  const float* W = (const float*)d_in[2];
  const float* b = (const float*)d_in[3];
  float* out = (float*)d_out;

  char* ws = (char*)d_ws;
  float* dis = (float*)ws;                          // 32 KB
  short* Ytf = (short*)(ws + 32768);                // 4 MB (frag-ordered)
  short* Yrm = (short*)(ws + 32768 + 4194304);      // 4 MB
  short* Wbf = (short*)(ws + 32768 + 2 * 4194304);  // 128 KB (frag-ordered)
  const size_t base = 32768 + 2ull * 4194304 + 131072;
  float* P = (float*)(ws + base);                   // splits * 8 MB

  const int splits = (ws_size >= base + 4ull * 8388608) ? 4 : 1;

  k_deg<<<2048, 256, 0, stream>>>(A, dis);
  k_prep<<<160, 256, 0, stream>>>(X, W, dis, Ytf, Yrm, Wbf);
  k_gemm<<<dim3(64, splits), 512, 0, stream>>>(A, Ytf, P, splits);
  k_out<<<512, 256, 0, stream>>>(P, Yrm, Wbf, dis, b, out, splits);
}